// Round 5
// baseline (186.224 us; speedup 1.0000x reference)
//
#include <hip/hip_runtime.h>

// TrajLoss: sum over i of (x[i]-pred[i])^2 + (y[i]-pred[i+1])^2
// N = 16,777,216; pred has N+1 elements. Memory-bound streaming reduction.
//
// R5: algebraic re-split. Sum_i (y_i - p_{i+1})^2 == Sum_{j=1..N} (y_{j-1} - p_j)^2.
// R6: all three streams nontemporal. 64.2 us.
// R7: grid 2048 persistent. 45.4 us.  R8: grid 1024, unroll 16: 44.96 us.
//    NOTE (seen at R13): R7 ran at VGPR 72 -> cap 16 waves/CU, so grid 2048
//    was never actually more-resident than 1024. TLP was untested until now.
// R9 FAILED: plain loads. nt is LOAD-BEARING on the bulk streams (L2 thrash).
// R10/R11 CONFOUNDED: per-iter divergent fixup load killed load batching.
// R12: aligned y4[i] + shfl_up, edge values preloaded to registers,
//    branch-free inner loop. 41.5-43.2 us (best). But VGPR 72->32: compiler
//    batches only ~2 iters now; alignment win partially offset by MLP loss.
//    VALU 7%, HBM 30%, occ 30% -> no single-pipe wall: latency-hiding bound.
// R13: grid 2048. With VGPR=32 (<=64 bucket = 8 waves/SIMD), 8 blocks/CU are
//    GENUINELY resident -> 32 waves/CU, 2x outstanding loads. 8 chunks/thread.
//    Predict occ -> ~60%, 41.5 -> ~35-37 us. If unchanged with doubled occ:
//    per-CU L2/L3 request-rate plateau -> roofline assessment next.

typedef float fx4 __attribute__((ext_vector_type(4)));

__global__ void TrajLoss_zero_kernel(float* out) {
    if (threadIdx.x == 0 && blockIdx.x == 0) out[0] = 0.0f;
}

// ---------------- specialized: n%4==0, n4 == 8*stride ----------------
__global__ __launch_bounds__(256) void TrajLoss_6141803233879_kernel(
    const float* __restrict__ pred,
    const float* __restrict__ x,
    const float* __restrict__ y,
    float* __restrict__ out,
    int n)    // total elements; n4 = n/4 == 8 * gridDim*blockDim exactly
{
    const int tid    = blockIdx.x * blockDim.x + threadIdx.x;
    const int stride = gridDim.x * blockDim.x;
    const int lane   = threadIdx.x & 63;

    float a0 = 0.0f, a1 = 0.0f, a2 = 0.0f, a3 = 0.0f;
    const fx4* x4 = (const fx4*)x;
    const fx4* p4 = (const fx4*)pred;
    const fx4* y4 = (const fx4*)y;

    if (tid == 0) {
        // Boundary term dy'_N = (y[n-1]-pred[n])^2.
        float dN = y[n - 1] - pred[n];
        a0 += dN * dN;
    }

    // Preload lane-0 wave-edge values y[4*(tid+k*stride)-1] (static indices
    // only -> registers). Other lanes never read edge[].
    float edge[8];
    if (lane == 0) {
        #pragma unroll
        for (int k = 0; k < 8; ++k) {
            int idx = ((tid + k * stride) << 2) - 1;
            edge[k] = y[idx < 0 ? 0 : idx];      // clamp: always in-bounds
        }
        if (tid == 0) edge[0] = pred[0];         // chunk 0: dy'_0 absent -> dy=0
    }

    #pragma unroll
    for (int k = 0; k < 8; ++k) {
        const int i = tid + k * stride;
        fx4 xv = __builtin_nontemporal_load(x4 + i);   // x[4i..4i+3]
        fx4 pa = __builtin_nontemporal_load(p4 + i);   // pred[4i..4i+3]
        fx4 yv = __builtin_nontemporal_load(y4 + i);   // y[4i..4i+3]  (ALIGNED)

        // y[4i-1]: lane-1's yv.w (lanes own consecutive chunks, lockstep k).
        float ym1 = __shfl_up(yv.w, 1, 64);
        ym1 = (lane == 0) ? edge[k] : ym1;             // branch-free select

        float dx, dy;
        dx = xv.x - pa.x; dy = ym1  - pa.x; a0 += dx*dx + dy*dy;
        dx = xv.y - pa.y; dy = yv.x - pa.y; a1 += dx*dx + dy*dy;
        dx = xv.z - pa.z; dy = yv.y - pa.z; a2 += dx*dx + dy*dy;
        dx = xv.w - pa.w; dy = yv.z - pa.w; a3 += dx*dx + dy*dy;
    }

    float acc = (a0 + a1) + (a2 + a3);

    #pragma unroll
    for (int off = 32; off > 0; off >>= 1)
        acc += __shfl_down(acc, off, 64);

    __shared__ float smem[4];
    const int wave = threadIdx.x >> 6;
    if (lane == 0) smem[wave] = acc;
    __syncthreads();

    if (threadIdx.x == 0) {
        float s = smem[0] + smem[1] + smem[2] + smem[3];
        atomicAdd(out, s);
    }
}

// ---------------- generic fallback: R8 kernel (proven 44.96 us) ----------------
__global__ __launch_bounds__(256) void TrajLoss_generic_kernel(
    const float* __restrict__ pred,
    const float* __restrict__ x,
    const float* __restrict__ y,
    float* __restrict__ out,
    int n4, int n)
{
    const int tid    = blockIdx.x * blockDim.x + threadIdx.x;
    const int stride = gridDim.x * blockDim.x;

    float a0 = 0.0f, a1 = 0.0f, a2 = 0.0f, a3 = 0.0f;
    const fx4* x4 = (const fx4*)x;
    const fx4* p4 = (const fx4*)pred;

    int i = tid;

    if (tid == 0) {
        float dx, dy;
        dx = x[0] - pred[0];                       a0 += dx*dx;
        dx = x[1] - pred[1]; dy = y[0] - pred[1];  a1 += dx*dx + dy*dy;
        dx = x[2] - pred[2]; dy = y[1] - pred[2];  a2 += dx*dx + dy*dy;
        dx = x[3] - pred[3]; dy = y[2] - pred[3];  a3 += dx*dx + dy*dy;
        if ((n & 3) == 0) {
            dy = y[n - 1] - pred[n];               a0 += dy*dy;
        } else {
            dy = y[(n4 << 2) - 1] - pred[n4 << 2]; a0 += dy*dy;
            for (int j = n4 << 2; j < n; ++j) {
                dx = x[j] - pred[j];
                dy = y[j] - pred[j + 1];
                a0 += dx*dx + dy*dy;
            }
        }
        i += stride;
    }

    #pragma unroll 16
    for (; i < n4; i += stride) {
        fx4 xv = __builtin_nontemporal_load(x4 + i);
        fx4 pa = __builtin_nontemporal_load(p4 + i);
        fx4 yb = __builtin_nontemporal_load((const fx4*)(y + (i << 2) - 1));
        float dx, dy;
        dx = xv.x - pa.x; dy = yb.x - pa.x; a0 += dx*dx + dy*dy;
        dx = xv.y - pa.y; dy = yb.y - pa.y; a1 += dx*dx + dy*dy;
        dx = xv.z - pa.z; dy = yb.z - pa.z; a2 += dx*dx + dy*dy;
        dx = xv.w - pa.w; dy = yb.w - pa.w; a3 += dx*dx + dy*dy;
    }

    float acc = (a0 + a1) + (a2 + a3);

    #pragma unroll
    for (int off = 32; off > 0; off >>= 1)
        acc += __shfl_down(acc, off, 64);

    __shared__ float smem[4];
    const int lane = threadIdx.x & 63;
    const int wave = threadIdx.x >> 6;
    if (lane == 0) smem[wave] = acc;
    __syncthreads();

    if (threadIdx.x == 0) {
        float s = smem[0] + smem[1] + smem[2] + smem[3];
        atomicAdd(out, s);
    }
}

extern "C" void kernel_launch(void* const* d_in, const int* in_sizes, int n_in,
                              void* d_out, int out_size, void* d_ws, size_t ws_size,
                              hipStream_t stream) {
    const float* pred = (const float*)d_in[0];   // N+1 floats
    const float* x    = (const float*)d_in[1];   // N floats
    const float* y    = (const float*)d_in[2];   // N floats
    float* out = (float*)d_out;

    const int n  = in_sizes[1];
    const int n4 = n >> 2;

    TrajLoss_zero_kernel<<<1, 64, 0, stream>>>(out);

    const int block = 256;
    const int grid  = 2048;          // VGPR<=64 -> 8 blocks/CU GENUINELY resident
    const int stride = grid * block; // 524,288

    if ((n & 3) == 0 && n4 == 8 * stride) {
        // N = 16,777,216 path: exactly 8 chunks/thread, uniform lockstep.
        TrajLoss_6141803233879_kernel<<<grid, block, 0, stream>>>(pred, x, y, out, n);
    } else {
        TrajLoss_generic_kernel<<<1024, block, 0, stream>>>(pred, x, y, out, n4, n);
    }
}

// Round 6
// 181.484 us; speedup vs baseline: 1.0261x; 1.0261x over previous
//
#include <hip/hip_runtime.h>

// TrajLoss: sum over i of (x[i]-pred[i])^2 + (y[i]-pred[i+1])^2
// N = 16,777,216; pred has N+1 elements. Memory-bound streaming reduction.
//
// R5: algebraic re-split: Sum_i (y_i-p_{i+1})^2 == Sum_{j=1..N} (y_{j-1}-p_j)^2.
// R6: nt on all three streams. 64.2 us.
// R7: grid 2048 persistent, VGPR 72: 45.4 us.  R8: grid 1024: 44.96 us.
// R9 FAILED: plain loads -> L2 thrash, 80 us. nt is LOAD-BEARING.
// R10/R11 CONFOUNDED: per-iter divergent fixup load killed batching (VGPR 16).
// R12: aligned y4 + shfl_up + preloaded edge regs, branch-free loop:
//    41.5 us BEST. But VGPR 72->32: alignment won while batching depth lost.
// R13 FAILED: grid 2048 (genuine 8 blocks/CU at VGPR 32). Occupancy 30->45%
//    yet 41.5->46.2 us: MORE waves HURT (stream-count contention). TLP is
//    refuted as the lever; per-wave MLP depth is the untested quadrant.
// R14: alignment + FORCED deep batching, grid 1024. 4 chunks/group into
//    named register sets, software-pipelined one group ahead (issue G(g+1)'s
//    12 nt loads before computing G(g)) -> 12-24 loads in flight per wave,
//    few fat waves (R7's regime) with R12's aligned pattern.
//    Validity: VGPR must be >=96 (if ~32, compiler re-serialized -> invalid,
//    escalate to sched_group_barrier). Predict 41.5 -> 34-37 us; if flat with
//    high VGPR, 4.85 TB/s is the 3-stream plateau -> roofline call.

typedef float fx4 __attribute__((ext_vector_type(4)));

__global__ void TrajLoss_zero_kernel(float* out) {
    if (threadIdx.x == 0 && blockIdx.x == 0) out[0] = 0.0f;
}

// ---------------- specialized: n%4==0, n4 == 16*stride ----------------
__global__ __launch_bounds__(256) void TrajLoss_6141803233879_kernel(
    const float* __restrict__ pred,
    const float* __restrict__ x,
    const float* __restrict__ y,
    float* __restrict__ out,
    int n)    // n4 = n/4 == 16 * gridDim*blockDim exactly
{
    const int tid    = blockIdx.x * blockDim.x + threadIdx.x;
    const int stride = gridDim.x * blockDim.x;   // 262,144
    const int lane   = threadIdx.x & 63;

    float a0 = 0.0f, a1 = 0.0f, a2 = 0.0f, a3 = 0.0f;
    const fx4* x4 = (const fx4*)x;
    const fx4* p4 = (const fx4*)pred;
    const fx4* y4 = (const fx4*)y;

    if (tid == 0) {
        // Boundary term dy'_N = (y[n-1]-pred[n])^2.
        float dN = y[n - 1] - pred[n];
        a0 += dN * dN;
    }

    // Lane-0 wave-edge values y[4*(tid+k*stride)-1], preloaded (static idx ->
    // registers). Other lanes never read edge[].
    float edge[16];
    if (lane == 0) {
        #pragma unroll
        for (int k = 0; k < 16; ++k) {
            int idx = ((tid + k * stride) << 2) - 1;
            edge[k] = y[idx < 0 ? 0 : idx];      // clamp: always in-bounds
        }
        if (tid == 0) edge[0] = pred[0];         // chunk 0: dy'_0 absent -> dy=0
    }

    // Two named register groups (A/B), 4 chunks each; pipeline 1 group ahead.
    fx4 xa[4], pa[4], ya[4];
    fx4 xb[4], pb[4], yb[4];

#define LOADG(X, P, Y, g)                                                  \
    {                                                                      \
        _Pragma("unroll")                                                  \
        for (int j = 0; j < 4; ++j) {                                      \
            const int i = tid + ((g) * 4 + j) * stride;                    \
            X[j] = __builtin_nontemporal_load(x4 + i);                     \
            P[j] = __builtin_nontemporal_load(p4 + i);                     \
            Y[j] = __builtin_nontemporal_load(y4 + i);                     \
        }                                                                  \
    }

#define COMPG(X, P, Y, g)                                                  \
    {                                                                      \
        _Pragma("unroll")                                                  \
        for (int j = 0; j < 4; ++j) {                                      \
            float ym1 = __shfl_up(Y[j].w, 1, 64);                          \
            ym1 = (lane == 0) ? edge[(g) * 4 + j] : ym1;                   \
            float dx, dy;                                                  \
            dx = X[j].x - P[j].x; dy = ym1    - P[j].x; a0 += dx*dx+dy*dy; \
            dx = X[j].y - P[j].y; dy = Y[j].x - P[j].y; a1 += dx*dx+dy*dy; \
            dx = X[j].z - P[j].z; dy = Y[j].y - P[j].z; a2 += dx*dx+dy*dy; \
            dx = X[j].w - P[j].w; dy = Y[j].z - P[j].w; a3 += dx*dx+dy*dy; \
        }                                                                  \
    }

    LOADG(xa, pa, ya, 0);        // fill
    LOADG(xb, pb, yb, 1);        // +1 group ahead
    COMPG(xa, pa, ya, 0);
    LOADG(xa, pa, ya, 2);
    COMPG(xb, pb, yb, 1);
    LOADG(xb, pb, yb, 3);
    COMPG(xa, pa, ya, 2);
    COMPG(xb, pb, yb, 3);        // drain

#undef LOADG
#undef COMPG

    float acc = (a0 + a1) + (a2 + a3);

    #pragma unroll
    for (int off = 32; off > 0; off >>= 1)
        acc += __shfl_down(acc, off, 64);

    __shared__ float smem[4];
    const int wave = threadIdx.x >> 6;
    if (lane == 0) smem[wave] = acc;
    __syncthreads();

    if (threadIdx.x == 0) {
        float s = smem[0] + smem[1] + smem[2] + smem[3];
        atomicAdd(out, s);
    }
}

// ---------------- generic fallback: R8 kernel (proven 44.96 us) ----------------
__global__ __launch_bounds__(256) void TrajLoss_generic_kernel(
    const float* __restrict__ pred,
    const float* __restrict__ x,
    const float* __restrict__ y,
    float* __restrict__ out,
    int n4, int n)
{
    const int tid    = blockIdx.x * blockDim.x + threadIdx.x;
    const int stride = gridDim.x * blockDim.x;

    float a0 = 0.0f, a1 = 0.0f, a2 = 0.0f, a3 = 0.0f;
    const fx4* x4 = (const fx4*)x;
    const fx4* p4 = (const fx4*)pred;

    int i = tid;

    if (tid == 0) {
        float dx, dy;
        dx = x[0] - pred[0];                       a0 += dx*dx;
        dx = x[1] - pred[1]; dy = y[0] - pred[1];  a1 += dx*dx + dy*dy;
        dx = x[2] - pred[2]; dy = y[1] - pred[2];  a2 += dx*dx + dy*dy;
        dx = x[3] - pred[3]; dy = y[2] - pred[3];  a3 += dx*dx + dy*dy;
        if ((n & 3) == 0) {
            dy = y[n - 1] - pred[n];               a0 += dy*dy;
        } else {
            dy = y[(n4 << 2) - 1] - pred[n4 << 2]; a0 += dy*dy;
            for (int j = n4 << 2; j < n; ++j) {
                dx = x[j] - pred[j];
                dy = y[j] - pred[j + 1];
                a0 += dx*dx + dy*dy;
            }
        }
        i += stride;
    }

    #pragma unroll 16
    for (; i < n4; i += stride) {
        fx4 xv = __builtin_nontemporal_load(x4 + i);
        fx4 pa = __builtin_nontemporal_load(p4 + i);
        fx4 yb = __builtin_nontemporal_load((const fx4*)(y + (i << 2) - 1));
        float dx, dy;
        dx = xv.x - pa.x; dy = yb.x - pa.x; a0 += dx*dx + dy*dy;
        dx = xv.y - pa.y; dy = yb.y - pa.y; a1 += dx*dx + dy*dy;
        dx = xv.z - pa.z; dy = yb.z - pa.z; a2 += dx*dx + dy*dy;
        dx = xv.w - pa.w; dy = yb.w - pa.w; a3 += dx*dx + dy*dy;
    }

    float acc = (a0 + a1) + (a2 + a3);

    #pragma unroll
    for (int off = 32; off > 0; off >>= 1)
        acc += __shfl_down(acc, off, 64);

    __shared__ float smem[4];
    const int lane = threadIdx.x & 63;
    const int wave = threadIdx.x >> 6;
    if (lane == 0) smem[wave] = acc;
    __syncthreads();

    if (threadIdx.x == 0) {
        float s = smem[0] + smem[1] + smem[2] + smem[3];
        atomicAdd(out, s);
    }
}

extern "C" void kernel_launch(void* const* d_in, const int* in_sizes, int n_in,
                              void* d_out, int out_size, void* d_ws, size_t ws_size,
                              hipStream_t stream) {
    const float* pred = (const float*)d_in[0];   // N+1 floats
    const float* x    = (const float*)d_in[1];   // N floats
    const float* y    = (const float*)d_in[2];   // N floats
    float* out = (float*)d_out;

    const int n  = in_sizes[1];
    const int n4 = n >> 2;

    TrajLoss_zero_kernel<<<1, 64, 0, stream>>>(out);

    const int block = 256;
    const int grid  = 1024;          // R13: more blocks HURT; 1024 is best
    const int stride = grid * block; // 262,144

    if ((n & 3) == 0 && n4 == 16 * stride) {
        // N = 16,777,216 path: exactly 16 chunks/thread, uniform lockstep.
        TrajLoss_6141803233879_kernel<<<grid, block, 0, stream>>>(pred, x, y, out, n);
    } else {
        TrajLoss_generic_kernel<<<grid, block, 0, stream>>>(pred, x, y, out, n4, n);
    }
}